// Round 11
// baseline (13651.886 us; speedup 1.0000x reference)
//
#include <hip/hip_runtime.h>
#include <hip/hip_bf16.h>
#include <cstdio>

typedef __hip_bfloat16 bf16;
typedef __attribute__((ext_vector_type(8))) short short8v;
typedef __attribute__((ext_vector_type(4))) float f32x4;
typedef __attribute__((ext_vector_type(2))) uint uint2v;
typedef __attribute__((ext_vector_type(4))) uint uint4v;
typedef __attribute__((ext_vector_type(4))) int  int4v;

#define T_WIN 1993      // N_WINDOWS
#define NSER 512
#define NTIME 2048
#define NGRP 32
#define FLAGS_INTS (4*8*NGRP)

// ---- raw buffer intrinsics (CK pattern) — count vmcnt ONLY, never lgkmcnt
__device__ uint4v llvm_amdgcn_raw_buffer_load_v4i32(int4v srsrc, uint voffset, uint soffset, int aux) __asm("llvm.amdgcn.raw.buffer.load.v4i32");
__device__ void   llvm_amdgcn_raw_buffer_store_v2i32(uint2v vdata, int4v srsrc, uint voffset, uint soffset, int aux) __asm("llvm.amdgcn.raw.buffer.store.v2i32");

__device__ __forceinline__ int4v make_srsrc(const void* p) {
  union { const void* p; unsigned long long u; } a; a.p = p;
  int4v r;
  r.x = (int)(a.u & 0xFFFFFFFFull);
  r.y = (int)(a.u >> 32);      // base[47:32]; stride = 0
  r.z = -1;                    // num_records = 0xFFFFFFFF (we clamp ourselves)
  r.w = 0x00020000;            // raw dword access
  return r;
}

__device__ __forceinline__ float sigmf(float x) { return __fdividef(1.f, 1.f + __expf(-x)); }
__device__ __forceinline__ float tanhf_fast(float x) { return 1.f - __fdividef(2.f, __expf(2.f*x) + 1.f); }
__device__ __forceinline__ ushort f2bfu(float f) {
  __hip_bfloat16 h = __float2bfloat16(f);
  return *reinterpret_cast<ushort*>(&h);
}

// ---------------- ES scan: 1 thread per series ----------------
__global__ void es_kernel(const float* __restrict__ y, const int* __restrict__ idxs,
                          const float* __restrict__ lev_sms, const float* __restrict__ seas_sms,
                          const float* __restrict__ init_seas,
                          float* __restrict__ levels, float* __restrict__ seas) {
  int s = blockIdx.x*blockDim.x + threadIdx.x;
  if (s >= NSER) return;
  int id = idxs[s];
  float ls = sigmf(lev_sms[id]);
  float ss = sigmf(seas_sms[id]);
  float buf[8];
  #pragma unroll
  for (int k=0;k<7;++k) buf[k] = __expf(init_seas[id*7+k]);
  buf[7] = buf[0];
  const float* yr = y + (size_t)s*NTIME;
  float* lr = levels + (size_t)s*NTIME;
  float* sr = seas + (size_t)s*NTIME;
  float lev = __fdividef(yr[0], buf[0]);
  lr[0] = lev;
  #pragma unroll
  for (int t=0;t<8;++t) sr[t] = buf[t];
  #pragma unroll 8
  for (int t=1;t<NTIME;++t) {
    float yt = yr[t];
    float st = buf[1];
    lev = ls*__fdividef(yt,st) + (1.f-ls)*lev;
    float ns = ss*__fdividef(yt,lev) + (1.f-ss)*st;
    #pragma unroll
    for (int k=0;k<7;++k) buf[k] = buf[k+1];
    buf[7] = ns;
    lr[t] = lev;
    if (t+7 < NTIME) sr[t+7] = ns;
  }
}

// ---------------- log(norm), log(levels) ----------------
__global__ void lnorm_kernel(const float* __restrict__ y, const float* __restrict__ seas,
                             const float* __restrict__ levels,
                             float* __restrict__ lnorm, float* __restrict__ llev) {
  int i = blockIdx.x*256 + threadIdx.x;
  lnorm[i] = __logf(__fdividef(y[i], seas[i]));
  llev[i]  = __logf(levels[i]);
}

// ---------------- windows: windows_y (out0) + RNN input xhat ----------------
__global__ void window_kernel(const float* __restrict__ lnorm, const float* __restrict__ llev,
                              const float* __restrict__ noise,
                              float* __restrict__ wy, ushort* __restrict__ xhat) {
  int idx = blockIdx.x*256 + threadIdx.x;   // (w*512 + s)*28 + k
  int k  = idx % 28;
  int rs = idx / 28;
  int s  = rs & 511;
  int w  = rs >> 9;
  float lv = llev[s*NTIME + 28 + w];
  const float* Ln = lnorm + s*NTIME;
  wy[idx]   = Ln[w+28+k] - lv;
  xhat[idx] = f2bfu(Ln[w+k] - lv + 0.001f*noise[idx]);
}

// ---------------- fused 4-layer pipelined LSTM scan (production) -----------
// r11: x loads + h stores via RAW BUFFER ops (vmcnt-only). The per-step
// "s_waitcnt lgkmcnt(0); s_barrier" then waits ONLY the LDS h-exchange —
// if the old pointer loads/stores were flat (lgkm-counted), this removes a
// full memory round-trip from every step (r10 ablation: loads +0.59 µs/step,
// stores +0.27 µs/step on the serial chain).
template<int KXS, int LAYER>
__device__ __forceinline__ void lstm_scan(
    const ushort* __restrict__ xin, ushort* __restrict__ hout,
    const float* __restrict__ Wih, const float* __restrict__ Whh,
    const float* __restrict__ bih, const float* __restrict__ bhh,
    const int j, const int g, int* __restrict__ flags)
{
  constexpr int KST  = KXS + 2;
  constexpr int D    = (KXS == 1) ? 28 : 64;
  constexpr int KX   = KXS * 32;
  constexpr int RATE = 1 << LAYER;
  constexpr int SRCR = (LAYER > 0) ? (RATE >> 1) : 1;

  __shared__ __align__(16) ushort hbuf[2][16*72];

  const int i    = threadIdx.x;
  const int lane = i & 63;
  const int wid  = i >> 6;
  const int n15  = lane & 15;
  const int kq   = lane >> 4;
  const int base = g * 16;
  const int wm   = i >> 4;
  const int wu   = (i & 15) * 4;
  const uint km  = (kq == 3) ? 0u : ~0u;

  const int4v xsr = make_srsrc(xin);
  const int4v hsr = make_srsrc(hout);

  short8v wfrag[4][KST];
  float bias[4];
  #pragma unroll
  for (int gg = 0; gg < 4; ++gg) {
    const int R = gg*64 + wid*16 + n15;
    bias[gg] = bih[R] + bhh[R];
    #pragma unroll
    for (int kk = 0; kk < KST; ++kk) {
      #pragma unroll
      for (int jj = 0; jj < 8; ++jj) {
        const int k = kk*32 + kq*8 + jj;
        float v;
        if (k < KX) v = (k < D) ? Wih[R*D + k] : 0.f;
        else        v = Whh[R*64 + (k - KX)];
        wfrag[gg][kk][jj] = (short)f2bfu(v);
      }
    }
  }

  for (int e = i; e < 1152; e += 256) hbuf[0][e] = 0;
  __syncthreads();

  const int nsteps = (T_WIN - 1 - j)/RATE + 1;
  const int u = wid*16 + n15;
  float cc[4] = {0.f, 0.f, 0.f, 0.f};

  int* myflag = &flags[(LAYER*8 + j)*NGRP + g];
  int* fp = nullptr;
  int seen0 = 0;
  int prodmax = 0x7fffffff;
  if constexpr (LAYER > 0) {
    const int pp0 = j % SRCR;
    fp = &flags[((LAYER-1)*8 + pp0)*NGRP + g];
    prodmax = (T_WIN - 1 - pp0)/SRCR + 1;
  }

  auto wait_for = [&](int t) __attribute__((always_inline)) {
    if constexpr (LAYER > 0) {
      const int tc = (t < T_WIN) ? t : (T_WIN - 1);
      int need = tc/SRCR + 1;
      need = (need < prodmax) ? need : prodmax;
      if (seen0 >= need) return;
      while (__hip_atomic_load(fp, __ATOMIC_RELAXED, __HIP_MEMORY_SCOPE_AGENT) < need)
        __builtin_amdgcn_s_sleep(8);
      seen0 = __hip_atomic_load(fp, __ATOMIC_ACQUIRE, __HIP_MEMORY_SCOPE_AGENT);
    }
  };

  // buffer-load x A-fragments for time t (clamped in-bounds)
  auto loadx = [&](int t, short8v* xf) __attribute__((always_inline)) {
    const int tc = (t < T_WIN) ? t : (T_WIN - 1);
    const uint row = (uint)(tc*512 + base + n15);
    if constexpr (D == 64) {
      const uint voff = row*128u + (uint)kq*16u;
      union { uint4v u; short8v s; } c0, c1;
      c0.u = llvm_amdgcn_raw_buffer_load_v4i32(xsr, voff,       0, 0);
      c1.u = llvm_amdgcn_raw_buffer_load_v4i32(xsr, voff + 64u, 0, 0);
      xf[0] = c0.s; xf[1] = c1.s;
    } else {
      const uint voff = row*56u + (uint)kq*16u;
      union { uint4v u; short8v s; } c0;
      c0.u = llvm_amdgcn_raw_buffer_load_v4i32(xsr, voff, 0, 0);
      c0.u.z &= km; c0.u.w &= km;   // zero K-pad (elems 4..7) for kq==3
      xf[0] = c0.s;
    }
  };

  auto stepc = [&](int S, short8v* xf, uint2v* hv) __attribute__((always_inline)) {
    const int p_ = S & 1;
    const int t_ = j + S*RATE;
    short8v hf0 = *reinterpret_cast<const short8v*>(&hbuf[p_][n15*72 + kq*8]);
    short8v hf1 = *reinterpret_cast<const short8v*>(&hbuf[p_][n15*72 + 32 + kq*8]);
    *hv = *reinterpret_cast<const uint2v*>(&hbuf[p_][wm*72 + wu]);
    f32x4 acc0 = {bias[0], bias[0], bias[0], bias[0]};
    f32x4 acc1 = {bias[1], bias[1], bias[1], bias[1]};
    f32x4 acc2 = {bias[2], bias[2], bias[2], bias[2]};
    f32x4 acc3 = {bias[3], bias[3], bias[3], bias[3]};
    #pragma unroll
    for (int kk = 0; kk < KXS; ++kk) {
      acc0 = __builtin_amdgcn_mfma_f32_16x16x32_bf16(xf[kk], wfrag[0][kk], acc0, 0, 0, 0);
      acc1 = __builtin_amdgcn_mfma_f32_16x16x32_bf16(xf[kk], wfrag[1][kk], acc1, 0, 0, 0);
      acc2 = __builtin_amdgcn_mfma_f32_16x16x32_bf16(xf[kk], wfrag[2][kk], acc2, 0, 0, 0);
      acc3 = __builtin_amdgcn_mfma_f32_16x16x32_bf16(xf[kk], wfrag[3][kk], acc3, 0, 0, 0);
    }
    acc0 = __builtin_amdgcn_mfma_f32_16x16x32_bf16(hf0, wfrag[0][KXS], acc0, 0, 0, 0);
    acc1 = __builtin_amdgcn_mfma_f32_16x16x32_bf16(hf0, wfrag[1][KXS], acc1, 0, 0, 0);
    acc2 = __builtin_amdgcn_mfma_f32_16x16x32_bf16(hf0, wfrag[2][KXS], acc2, 0, 0, 0);
    acc3 = __builtin_amdgcn_mfma_f32_16x16x32_bf16(hf0, wfrag[3][KXS], acc3, 0, 0, 0);
    acc0 = __builtin_amdgcn_mfma_f32_16x16x32_bf16(hf1, wfrag[0][KXS+1], acc0, 0, 0, 0);
    acc1 = __builtin_amdgcn_mfma_f32_16x16x32_bf16(hf1, wfrag[1][KXS+1], acc1, 0, 0, 0);
    acc2 = __builtin_amdgcn_mfma_f32_16x16x32_bf16(hf1, wfrag[2][KXS+1], acc2, 0, 0, 0);
    acc3 = __builtin_amdgcn_mfma_f32_16x16x32_bf16(hf1, wfrag[3][KXS+1], acc3, 0, 0, 0);
    loadx(t_ + 4*RATE, xf);
    #pragma unroll
    for (int r = 0; r < 4; ++r) {
      const float zi = acc0[r], zf = acc1[r], zg = acc2[r], zo = acc3[r];
      cc[r] = sigmf(zf)*cc[r] + sigmf(zi)*tanhf_fast(zg);
      const float h_ = sigmf(zo)*tanhf_fast(cc[r]);
      hbuf[p_^1][(kq*4 + r)*72 + u] = f2bfu(h_);
    }
    __builtin_amdgcn_sched_barrier(0);
    asm volatile("s_waitcnt lgkmcnt(0)");
    __builtin_amdgcn_sched_barrier(0);
    __builtin_amdgcn_s_barrier();
  };

  auto sth = [&](int t, uint2v hv) __attribute__((always_inline)) {
    const uint voff = (uint)(t*512 + base + wm)*128u + (uint)wu*2u;
    llvm_amdgcn_raw_buffer_store_v2i32(hv, hsr, voff, 0, 0);
  };

  short8v xf0[KXS], xf1[KXS], xf2[KXS], xf3[KXS];
  uint2v hh0, hh1, hh2, hh3;

  wait_for(j + 7*RATE);
  loadx(j,          xf0);
  loadx(j +   RATE, xf1);
  loadx(j + 2*RATE, xf2);
  loadx(j + 3*RATE, xf3);

  stepc(0, xf0, &hh0);
  stepc(1, xf1, &hh1);
  stepc(2, xf2, &hh2);
  stepc(3, xf3, &hh3);
  sth(j,          hh1);
  sth(j +   RATE, hh2);
  sth(j + 2*RATE, hh3);

  int B = 4;
  for (; B + 4 <= nsteps; B += 4) {
    wait_for(j + (B + 7)*RATE);
    stepc(B+0, xf0, &hh0);
    stepc(B+1, xf1, &hh1);
    stepc(B+2, xf2, &hh2);
    stepc(B+3, xf3, &hh3);
    sth(j + (B-1)*RATE, hh0);
    sth(j + (B  )*RATE, hh1);
    sth(j + (B+1)*RATE, hh2);
    sth(j + (B+2)*RATE, hh3);
    if constexpr (LAYER < 3) {
      if ((B & 7) == 4) {
        asm volatile("s_waitcnt vmcnt(0)");
        __builtin_amdgcn_s_barrier();
        if (i == 0)
          __hip_atomic_store(myflag, B+3, __ATOMIC_RELEASE, __HIP_MEMORY_SCOPE_AGENT);
      }
    }
  }
  for (; B < nsteps; ++B) {
    wait_for(j + (B + 4)*RATE);
    short8v xfT[KXS];
    const int r_ = B & 3;
    #pragma unroll
    for (int q = 0; q < KXS; ++q)
      xfT[q] = (r_ == 0) ? xf0[q] : (r_ == 1) ? xf1[q] : (r_ == 2) ? xf2[q] : xf3[q];
    uint2v hvT;
    stepc(B, xfT, &hvT);
    sth(j + (B-1)*RATE, hvT);
  }

  {
    const int pF = nsteps & 1;
    const int tF = j + (nsteps - 1)*RATE;
    uint2v hv = *reinterpret_cast<const uint2v*>(&hbuf[pF][wm*72 + wu]);
    sth(tF, hv);
  }
  if constexpr (LAYER < 3) {
    asm volatile("s_waitcnt vmcnt(0)");
    __builtin_amdgcn_s_barrier();
    if (i == 0)
      __hip_atomic_store(myflag, nsteps, __ATOMIC_RELEASE, __HIP_MEMORY_SCOPE_AGENT);
  }
}

__global__ __launch_bounds__(256, 2)
void lstm_fused(const ushort* __restrict__ xhat,
                ushort* __restrict__ h1, ushort* __restrict__ h2, ushort* __restrict__ h4,
                const float* __restrict__ Wih0, const float* __restrict__ Wih_rest,
                const float* __restrict__ Whh_all,
                const float* __restrict__ bih_all, const float* __restrict__ bhh_all,
                int* __restrict__ flags)
{
  const int bid = blockIdx.x;
  ushort* h3 = h1;
  if (bid < 32) {
    lstm_scan<1,0>(xhat, h1, Wih0, Whh_all, bih_all, bhh_all,
                   0, bid, flags);
  } else if (bid < 96) {
    lstm_scan<2,1>(h1, h2, Wih_rest, Whh_all + 256*64, bih_all + 256, bhh_all + 256,
                   (bid-32) >> 5, (bid-32) & 31, flags);
  } else if (bid < 224) {
    lstm_scan<2,2>(h2, h3, Wih_rest + 256*64, Whh_all + 2*256*64, bih_all + 2*256, bhh_all + 2*256,
                   (bid-96) >> 5, (bid-96) & 31, flags);
  } else {
    lstm_scan<2,3>(h3, h4, Wih_rest + 2*256*64, Whh_all + 3*256*64, bih_all + 3*256, bhh_all + 3*256,
                   (bid-224) >> 5, (bid-224) & 31, flags);
  }
}

// ============ DIAGNOSTICS (dead scratch; loads-only L1 replicas) ===========
// MODE 0: plain-pointer loads + step barrier        (r10 anchor: 1.12 µs/step)
// MODE 1: buffer loads + step barrier               (theory: ~0.55 µs/step)
// MODE 2: buffer loads, NO lgkm-wait / NO barrier   (lower bound)
template<int MODE>
__global__ __launch_bounds__(256, 1)
void lstm_diag(const ushort* __restrict__ xin, ushort* __restrict__ hout,
               const float* __restrict__ Wih, const float* __restrict__ Whh,
               const float* __restrict__ bih, const float* __restrict__ bhh,
               const int nsteps)
{
  __shared__ __align__(16) ushort hbuf[2][16*72];
  const int i = threadIdx.x;
  const int lane = i & 63, wid = i >> 6, n15 = lane & 15, kq = lane >> 4;
  const int base = blockIdx.x * 16;
  const int wm = i >> 4, wu = (i & 15) * 4;
  const uint km = (kq == 3) ? 0u : ~0u;
  const int4v xsr = make_srsrc(xin);

  short8v wfrag[4][3];
  float bias[4];
  #pragma unroll
  for (int gg = 0; gg < 4; ++gg) {
    const int R = gg*64 + wid*16 + n15;
    bias[gg] = bih[R] + bhh[R];
    #pragma unroll
    for (int kk = 0; kk < 3; ++kk) {
      #pragma unroll
      for (int jj = 0; jj < 8; ++jj) {
        const int k = kk*32 + kq*8 + jj;
        float v;
        if (k < 32) v = (k < 28) ? Wih[R*28 + k] : 0.f;
        else        v = Whh[R*64 + (k - 32)];
        wfrag[gg][kk][jj] = (short)f2bfu(v);
      }
    }
  }
  for (int e = i; e < 1152; e += 256) hbuf[0][e] = 0;
  __syncthreads();

  const int u = wid*16 + n15;
  float cc4[4] = {0.f,0.f,0.f,0.f};

  auto loadx = [&](int t, short8v* xf) __attribute__((always_inline)) {
    const int tc = (t < T_WIN) ? t : (T_WIN - 1);
    if constexpr (MODE == 0) {
      const ushort* p = xin + ((size_t)tc*512 + base + n15)*28 + kq*8;
      ushort4 a = *reinterpret_cast<const ushort4*>(p);
      ushort4 b = *reinterpret_cast<const ushort4*>(p + 4);
      short8v r;
      r[0]=(short)a.x; r[1]=(short)a.y; r[2]=(short)a.z; r[3]=(short)a.w;
      r[4]=(short)(ushort)(b.x & km); r[5]=(short)(ushort)(b.y & km);
      r[6]=(short)(ushort)(b.z & km); r[7]=(short)(ushort)(b.w & km);
      xf[0] = r;
    } else {
      const uint voff = (uint)(tc*512 + base + n15)*56u + (uint)kq*16u;
      union { uint4v u; short8v s; } c0;
      c0.u = llvm_amdgcn_raw_buffer_load_v4i32(xsr, voff, 0, 0);
      c0.u.z &= km; c0.u.w &= km;
      xf[0] = c0.s;
    }
  };

  auto stepc = [&](int S, short8v* xf) __attribute__((always_inline)) {
    const int p_ = S & 1;
    short8v hf0 = *reinterpret_cast<const short8v*>(&hbuf[p_][n15*72 + kq*8]);
    short8v hf1 = *reinterpret_cast<const short8v*>(&hbuf[p_][n15*72 + 32 + kq*8]);
    uint2v hv = *reinterpret_cast<const uint2v*>(&hbuf[p_][wm*72 + wu]);
    asm volatile("" :: "v"(hv.x), "v"(hv.y));   // keep ds_read live (rule #17)
    f32x4 a0 = {bias[0],bias[0],bias[0],bias[0]};
    f32x4 a1 = {bias[1],bias[1],bias[1],bias[1]};
    f32x4 a2 = {bias[2],bias[2],bias[2],bias[2]};
    f32x4 a3 = {bias[3],bias[3],bias[3],bias[3]};
    a0 = __builtin_amdgcn_mfma_f32_16x16x32_bf16(xf[0], wfrag[0][0], a0, 0, 0, 0);
    a1 = __builtin_amdgcn_mfma_f32_16x16x32_bf16(xf[0], wfrag[1][0], a1, 0, 0, 0);
    a2 = __builtin_amdgcn_mfma_f32_16x16x32_bf16(xf[0], wfrag[2][0], a2, 0, 0, 0);
    a3 = __builtin_amdgcn_mfma_f32_16x16x32_bf16(xf[0], wfrag[3][0], a3, 0, 0, 0);
    a0 = __builtin_amdgcn_mfma_f32_16x16x32_bf16(hf0, wfrag[0][1], a0, 0, 0, 0);
    a1 = __builtin_amdgcn_mfma_f32_16x16x32_bf16(hf0, wfrag[1][1], a1, 0, 0, 0);
    a2 = __builtin_amdgcn_mfma_f32_16x16x32_bf16(hf0, wfrag[2][1], a2, 0, 0, 0);
    a3 = __builtin_amdgcn_mfma_f32_16x16x32_bf16(hf0, wfrag[3][1], a3, 0, 0, 0);
    a0 = __builtin_amdgcn_mfma_f32_16x16x32_bf16(hf1, wfrag[0][2], a0, 0, 0, 0);
    a1 = __builtin_amdgcn_mfma_f32_16x16x32_bf16(hf1, wfrag[1][2], a1, 0, 0, 0);
    a2 = __builtin_amdgcn_mfma_f32_16x16x32_bf16(hf1, wfrag[2][2], a2, 0, 0, 0);
    a3 = __builtin_amdgcn_mfma_f32_16x16x32_bf16(hf1, wfrag[3][2], a3, 0, 0, 0);
    loadx(S + 4, xf);
    #pragma unroll
    for (int r = 0; r < 4; ++r) {
      cc4[r] = sigmf(a1[r])*cc4[r] + sigmf(a0[r])*tanhf_fast(a2[r]);
      float h_ = sigmf(a3[r])*tanhf_fast(cc4[r]);
      hbuf[p_^1][(kq*4 + r)*72 + u] = f2bfu(h_);
    }
    __builtin_amdgcn_sched_barrier(0);
    if constexpr (MODE != 2) {
      asm volatile("s_waitcnt lgkmcnt(0)");
      __builtin_amdgcn_sched_barrier(0);
      __builtin_amdgcn_s_barrier();
    }
  };

  short8v xf0[1], xf1[1], xf2[1], xf3[1];
  loadx(0, xf0); loadx(1, xf1); loadx(2, xf2); loadx(3, xf3);
  int B = 0;
  for (; B + 4 <= nsteps; B += 4) {
    stepc(B+0, xf0);
    stepc(B+1, xf1);
    stepc(B+2, xf2);
    stepc(B+3, xf3);
  }
  for (; B < nsteps; ++B) {
    short8v xfT[1];
    const int r_ = B & 3;
    xfT[0] = (r_ == 0) ? xf0[0] : (r_ == 1) ? xf1[0] : (r_ == 2) ? xf2[0] : xf3[0];
    stepc(B, xfT);
  }
  {
    const int pF = nsteps & 1;
    uint2 hv = *reinterpret_cast<const uint2*>(&hbuf[pF][wm*72 + wu]);
    *reinterpret_cast<uint2*>(&hout[((size_t)((nsteps-1) & 1023)*512 + base + wm)*64 + wu]) = hv;
  }
}

// ---------------- adapter: out1 = (h4+h2) @ adW.T + adb ----------------
__global__ __launch_bounds__(256) void adapter_kernel(const ushort* __restrict__ h4, const ushort* __restrict__ h2,
      const float* __restrict__ adW, const float* __restrict__ adb, float* __restrict__ out) {
  __shared__ __align__(16) float xrow[64*64];
  const int i = threadIdx.x;
  const int total = T_WIN*512;
  const int base = blockIdx.x * 64;
  for (int e = i; e < 64*64; e += 256) {
    int r = e >> 6;
    size_t gi = (size_t)(base + r)*64 + (e & 63);
    float v = 0.f;
    if (base + r < total) {
      __hip_bfloat16 a = *reinterpret_cast<const __hip_bfloat16*>(h4 + gi);
      __hip_bfloat16 b = *reinterpret_cast<const __hip_bfloat16*>(h2 + gi);
      v = __bfloat162float(a) + __bfloat162float(b);
    }
    xrow[e] = v;
  }
  const int o  = i & 31;
  const int rg = i >> 5;
  float w[64]; float bo = 0.f;
  if (o < 28) {
    #pragma unroll
    for (int uu=0;uu<64;++uu) w[uu] = adW[o*64+uu];
    bo = adb[o];
  }
  __syncthreads();
  if (o < 28) {
    #pragma unroll
    for (int rr=0; rr<8; ++rr) {
      int r = rg*8 + rr;
      if (base + r >= total) break;
      const float4* xp = (const float4*)(&xrow[r*64]);
      float a0 = bo, a1 = 0.f, a2 = 0.f, a3 = 0.f;
      #pragma unroll
      for (int q=0;q<16;++q) {
        float4 xv = xp[q];
        a0 += w[4*q+0]*xv.x; a1 += w[4*q+1]*xv.y;
        a2 += w[4*q+2]*xv.z; a3 += w[4*q+3]*xv.w;
      }
      out[(size_t)(base+r)*28 + o] = (a0+a1)+(a2+a3);
    }
  }
}

extern "C" void kernel_launch(void* const* d_in, const int* in_sizes, int n_in,
                              void* d_out, int out_size, void* d_ws, size_t ws_size,
                              hipStream_t stream) {
  const float* y         = (const float*)d_in[0];
  const int*   idxs      = (const int*)d_in[1];
  const float* noise     = (const float*)d_in[2];
  const float* lev_sms   = (const float*)d_in[3];
  const float* seas_sms  = (const float*)d_in[4];
  const float* init_seas = (const float*)d_in[5];
  const float* Wih0      = (const float*)d_in[6];
  const float* Wih_rest  = (const float*)d_in[7];
  const float* Whh_all   = (const float*)d_in[8];
  const float* bih_all   = (const float*)d_in[9];
  const float* bhh_all   = (const float*)d_in[10];
  const float* adW       = (const float*)d_in[11];
  const float* adb       = (const float*)d_in[12];

  const size_t NWIN28 = (size_t)T_WIN*512*28;
  const size_t NWIN64 = (size_t)T_WIN*512*64;
  float* out_wy   = (float*)d_out;
  float* out_yhat = out_wy + NWIN28;
  float* out_lev  = out_yhat + NWIN28;

  int*   flags = (int*)d_ws;                       // 4 KiB reserved
  float* seas  = (float*)((char*)d_ws + 4096);
  float* lnorm = seas  + (size_t)NSER*NTIME;
  float* llev  = lnorm + (size_t)NSER*NTIME;
  ushort* xhat = (ushort*)(llev + (size_t)NSER*NTIME);
  ushort* h1   = (ushort*)((char*)xhat + NWIN28*2);
  ushort* h2   = (ushort*)((char*)h1 + NWIN64*2);
  ushort* h4   = (ushort*)((char*)h2 + NWIN64*2);

  size_t need = 4096 + (size_t)3*NSER*NTIME*4 + NWIN28*2 + 3*NWIN64*2;
  if (ws_size < need) {
    fprintf(stderr, "kernel_launch: ws_size %zu < needed %zu\n", ws_size, need);
    return;
  }

  hipMemsetAsync(flags, 0, FLAGS_INTS*sizeof(int), stream);
  es_kernel<<<2,256,0,stream>>>(y, idxs, lev_sms, seas_sms, init_seas, out_lev, seas);
  lnorm_kernel<<<(NSER*NTIME)/256,256,0,stream>>>(y, seas, out_lev, lnorm, llev);
  window_kernel<<<NWIN28/256,256,0,stream>>>(lnorm, llev, noise, out_wy, xhat);

  lstm_fused<<<480,256,0,stream>>>(xhat, h1, h2, h4, Wih0, Wih_rest, Whh_all,
                                   bih_all, bhh_all, flags);

  adapter_kernel<<<(T_WIN*512)/64,256,0,stream>>>(h4, h2, adW, adb, out_yhat);

  // ---- diagnostics (dead scratch; h1 unused after adapter) ----
  lstm_diag<0><<<32,256,0,stream>>>(xhat, h1, Wih0, Whh_all, bih_all, bhh_all, 3000);
  lstm_diag<1><<<32,256,0,stream>>>(xhat, h1, Wih0, Whh_all, bih_all, bhh_all, 3000);
  lstm_diag<2><<<32,256,0,stream>>>(xhat, h1, Wih0, Whh_all, bih_all, bhh_all, 3000);
}

// Round 12
// 4283.625 us; speedup vs baseline: 3.1870x; 3.1870x over previous
//
#include <hip/hip_runtime.h>
#include <hip/hip_bf16.h>
#include <cstdio>

typedef __hip_bfloat16 bf16;
typedef __attribute__((ext_vector_type(8))) short short8v;
typedef __attribute__((ext_vector_type(4))) float f32x4;

#define T_WIN 1993      // N_WINDOWS
#define NSER 512
#define NTIME 2048
#define NGRP 32
#define FLAGS_INTS (4*8*NGRP)

// s_waitcnt immediates (gfx9 encoding: vm[3:0]|exp[6:4]|lgkm[11:8]|vm[5:4]@[15:14])
#define WAIT_LGKM0 0xC07F   // lgkmcnt(0) only (vm=63, exp=7)
#define WAIT_VM0   0x0F70   // vmcnt(0) only (lgkm=15, exp=7)

__device__ __forceinline__ float sigmf(float x) { return __fdividef(1.f, 1.f + __expf(-x)); }
__device__ __forceinline__ float tanhf_fast(float x) { return 1.f - __fdividef(2.f, __expf(2.f*x) + 1.f); }
__device__ __forceinline__ ushort f2bfu(float f) {
  __hip_bfloat16 h = __float2bfloat16(f);
  return *reinterpret_cast<ushort*>(&h);
}

// ---------------- ES scan: 1 thread per series ----------------
__global__ void es_kernel(const float* __restrict__ y, const int* __restrict__ idxs,
                          const float* __restrict__ lev_sms, const float* __restrict__ seas_sms,
                          const float* __restrict__ init_seas,
                          float* __restrict__ levels, float* __restrict__ seas) {
  int s = blockIdx.x*blockDim.x + threadIdx.x;
  if (s >= NSER) return;
  int id = idxs[s];
  float ls = sigmf(lev_sms[id]);
  float ss = sigmf(seas_sms[id]);
  float buf[8];
  #pragma unroll
  for (int k=0;k<7;++k) buf[k] = __expf(init_seas[id*7+k]);
  buf[7] = buf[0];
  const float* yr = y + (size_t)s*NTIME;
  float* lr = levels + (size_t)s*NTIME;
  float* sr = seas + (size_t)s*NTIME;
  float lev = __fdividef(yr[0], buf[0]);
  lr[0] = lev;
  #pragma unroll
  for (int t=0;t<8;++t) sr[t] = buf[t];
  #pragma unroll 8
  for (int t=1;t<NTIME;++t) {
    float yt = yr[t];
    float st = buf[1];
    lev = ls*__fdividef(yt,st) + (1.f-ls)*lev;
    float ns = ss*__fdividef(yt,lev) + (1.f-ss)*st;
    #pragma unroll
    for (int k=0;k<7;++k) buf[k] = buf[k+1];
    buf[7] = ns;
    lr[t] = lev;
    if (t+7 < NTIME) sr[t+7] = ns;
  }
}

// ---------------- log(norm), log(levels) ----------------
__global__ void lnorm_kernel(const float* __restrict__ y, const float* __restrict__ seas,
                             const float* __restrict__ levels,
                             float* __restrict__ lnorm, float* __restrict__ llev) {
  int i = blockIdx.x*256 + threadIdx.x;
  lnorm[i] = __logf(__fdividef(y[i], seas[i]));
  llev[i]  = __logf(levels[i]);
}

// ---------------- windows: windows_y (out0) + RNN input xhat ----------------
__global__ void window_kernel(const float* __restrict__ lnorm, const float* __restrict__ llev,
                              const float* __restrict__ noise,
                              float* __restrict__ wy, ushort* __restrict__ xhat) {
  int idx = blockIdx.x*256 + threadIdx.x;   // (w*512 + s)*28 + k
  int k  = idx % 28;
  int rs = idx / 28;
  int s  = rs & 511;
  int w  = rs >> 9;
  float lv = llev[s*NTIME + 28 + w];
  const float* Ln = lnorm + s*NTIME;
  wy[idx]   = Ln[w+28+k] - lv;
  xhat[idx] = f2bfu(Ln[w+k] - lv + 0.001f*noise[idx]);
}

// ---------------- fused 4-layer pipelined LSTM scan (production) -----------
// r12: ZERO register-dest VMEM inside steady-state steps (r10 ablation:
// per-step loads +0.59 µs, stores +0.27 µs on the serial chain; every
// register-prefetch scheme failed to hide them).
//   x: global->regs at 4-step chunk boundaries (for chunk c+2), regs->LDS
//      ring at the next boundary (4-step counted vmcnt slack, T14 pattern);
//      steps read x via ds_read_b128 from the ring (lgkm, fine-grained).
//   h: burst-stored at chunk end (boundary region).
//   per-step sync: builtin s_waitcnt(lgkm0) + raw s_barrier (no vmcnt drain).
template<int KXS, int LAYER>
__device__ __forceinline__ void lstm_scan(
    const ushort* __restrict__ xin, ushort* __restrict__ hout,
    const float* __restrict__ Wih, const float* __restrict__ Whh,
    const float* __restrict__ bih, const float* __restrict__ bhh,
    const int j, const int g, int* __restrict__ flags)
{
  constexpr int KST  = KXS + 2;
  constexpr int D    = (KXS == 1) ? 28 : 64;
  constexpr int KX   = KXS * 32;
  constexpr int RATE = 1 << LAYER;
  constexpr int SRCR = (LAYER > 0) ? (RATE >> 1) : 1;
  constexpr int XSTR = (KXS == 1) ? 40 : 72;   // LDS x row stride (units); 80/144 B: 16B-aligned

  __shared__ __align__(16) ushort hbuf[2][16*72];
  __shared__ __align__(16) ushort xring[2][4][16*XSTR];

  const int i    = threadIdx.x;
  const int lane = i & 63;
  const int wid  = i >> 6;
  const int n15  = lane & 15;
  const int kq   = lane >> 4;
  const int base = g * 16;
  const int wm   = i >> 4;
  const int wu   = (i & 15) * 4;
  const int sr14 = i / 14, sc14 = i - sr14*14;   // D==28 staging coords (i<224)

  short8v wfrag[4][KST];
  float bias[4];
  #pragma unroll
  for (int gg = 0; gg < 4; ++gg) {
    const int R = gg*64 + wid*16 + n15;
    bias[gg] = bih[R] + bhh[R];
    #pragma unroll
    for (int kk = 0; kk < KST; ++kk) {
      #pragma unroll
      for (int jj = 0; jj < 8; ++jj) {
        const int k = kk*32 + kq*8 + jj;
        float v;
        if (k < KX) v = (k < D) ? Wih[R*D + k] : 0.f;
        else        v = Whh[R*64 + (k - KX)];
        wfrag[gg][kk][jj] = (short)f2bfu(v);
      }
    }
  }

  for (int e = i; e < 1152; e += 256) hbuf[0][e] = 0;
  for (int e = i; e < 2*4*16*XSTR; e += 256) ((ushort*)xring)[e] = 0;  // incl. K-pad
  __syncthreads();

  const int nsteps = (T_WIN - 1 - j)/RATE + 1;
  const int u = wid*16 + n15;
  float cc[4] = {0.f, 0.f, 0.f, 0.f};

  int* myflag = &flags[(LAYER*8 + j)*NGRP + g];
  int* fp = nullptr;
  int seen0 = 0;
  int prodmax = 0x7fffffff;
  if constexpr (LAYER > 0) {
    const int pp0 = j % SRCR;
    fp = &flags[((LAYER-1)*8 + pp0)*NGRP + g];
    prodmax = (T_WIN - 1 - pp0)/SRCR + 1;
  }

  auto wait_for = [&](int t) __attribute__((always_inline)) {
    if constexpr (LAYER > 0) {
      const int tc = (t < T_WIN) ? t : (T_WIN - 1);
      int need = tc/SRCR + 1;
      need = (need < prodmax) ? need : prodmax;
      if (seen0 >= need) return;
      while (__hip_atomic_load(fp, __ATOMIC_RELAXED, __HIP_MEMORY_SCOPE_AGENT) < need)
        __builtin_amdgcn_s_sleep(8);
      seen0 = __hip_atomic_load(fp, __ATOMIC_ACQUIRE, __HIP_MEMORY_SCOPE_AGENT);
    }
  };

  // -------- chunk staging (4 t's per chunk) --------
  uint  g28[4];    // D==28 staging regs
  uint2 g64[4];    // D==64 staging regs

  auto loadG = [&](int chunk) __attribute__((always_inline)) {
    #pragma unroll
    for (int q = 0; q < 4; ++q) {
      int t = j + (chunk*4 + q)*RATE;
      const int tc = (t < T_WIN) ? t : (T_WIN - 1);
      if constexpr (KXS == 1) {
        if (i < 224)
          g28[q] = *reinterpret_cast<const uint*>(xin + ((size_t)tc*512 + base + sr14)*28 + sc14*2);
      } else {
        g64[q] = *reinterpret_cast<const uint2*>(xin + ((size_t)tc*512 + base + (i>>4))*64 + (i&15)*4);
      }
    }
  };
  auto writeG = [&](int buf) __attribute__((always_inline)) {
    #pragma unroll
    for (int q = 0; q < 4; ++q) {
      if constexpr (KXS == 1) {
        if (i < 224)
          *reinterpret_cast<uint*>(&xring[buf][q][sr14*40 + sc14*2]) = g28[q];
      } else {
        *reinterpret_cast<uint2*>(&xring[buf][q][(i>>4)*72 + (i&15)*4]) = g64[q];
      }
    }
  };

  // -------- one recurrence step: LDS-only --------
  auto stepc = [&](int S, uint2* hv) __attribute__((always_inline)) {
    const int p_ = S & 1;
    const ushort* xr = xring[(S>>2)&1][S&3];
    short8v xa = *reinterpret_cast<const short8v*>(xr + n15*XSTR + kq*8);
    short8v xb;
    if constexpr (KXS == 2) xb = *reinterpret_cast<const short8v*>(xr + n15*XSTR + 32 + kq*8);
    short8v hf0 = *reinterpret_cast<const short8v*>(&hbuf[p_][n15*72 + kq*8]);
    short8v hf1 = *reinterpret_cast<const short8v*>(&hbuf[p_][n15*72 + 32 + kq*8]);
    *hv = *reinterpret_cast<const uint2*>(&hbuf[p_][wm*72 + wu]);
    f32x4 acc0 = {bias[0], bias[0], bias[0], bias[0]};
    f32x4 acc1 = {bias[1], bias[1], bias[1], bias[1]};
    f32x4 acc2 = {bias[2], bias[2], bias[2], bias[2]};
    f32x4 acc3 = {bias[3], bias[3], bias[3], bias[3]};
    acc0 = __builtin_amdgcn_mfma_f32_16x16x32_bf16(xa, wfrag[0][0], acc0, 0, 0, 0);
    acc1 = __builtin_amdgcn_mfma_f32_16x16x32_bf16(xa, wfrag[1][0], acc1, 0, 0, 0);
    acc2 = __builtin_amdgcn_mfma_f32_16x16x32_bf16(xa, wfrag[2][0], acc2, 0, 0, 0);
    acc3 = __builtin_amdgcn_mfma_f32_16x16x32_bf16(xa, wfrag[3][0], acc3, 0, 0, 0);
    if constexpr (KXS == 2) {
      acc0 = __builtin_amdgcn_mfma_f32_16x16x32_bf16(xb, wfrag[0][1], acc0, 0, 0, 0);
      acc1 = __builtin_amdgcn_mfma_f32_16x16x32_bf16(xb, wfrag[1][1], acc1, 0, 0, 0);
      acc2 = __builtin_amdgcn_mfma_f32_16x16x32_bf16(xb, wfrag[2][1], acc2, 0, 0, 0);
      acc3 = __builtin_amdgcn_mfma_f32_16x16x32_bf16(xb, wfrag[3][1], acc3, 0, 0, 0);
    }
    acc0 = __builtin_amdgcn_mfma_f32_16x16x32_bf16(hf0, wfrag[0][KXS], acc0, 0, 0, 0);
    acc1 = __builtin_amdgcn_mfma_f32_16x16x32_bf16(hf0, wfrag[1][KXS], acc1, 0, 0, 0);
    acc2 = __builtin_amdgcn_mfma_f32_16x16x32_bf16(hf0, wfrag[2][KXS], acc2, 0, 0, 0);
    acc3 = __builtin_amdgcn_mfma_f32_16x16x32_bf16(hf0, wfrag[3][KXS], acc3, 0, 0, 0);
    acc0 = __builtin_amdgcn_mfma_f32_16x16x32_bf16(hf1, wfrag[0][KXS+1], acc0, 0, 0, 0);
    acc1 = __builtin_amdgcn_mfma_f32_16x16x32_bf16(hf1, wfrag[1][KXS+1], acc1, 0, 0, 0);
    acc2 = __builtin_amdgcn_mfma_f32_16x16x32_bf16(hf1, wfrag[2][KXS+1], acc2, 0, 0, 0);
    acc3 = __builtin_amdgcn_mfma_f32_16x16x32_bf16(hf1, wfrag[3][KXS+1], acc3, 0, 0, 0);
    #pragma unroll
    for (int r = 0; r < 4; ++r) {
      const float zi = acc0[r], zf = acc1[r], zg = acc2[r], zo = acc3[r];
      cc[r] = sigmf(zf)*cc[r] + sigmf(zi)*tanhf_fast(zg);
      const float h_ = sigmf(zo)*tanhf_fast(cc[r]);
      hbuf[p_^1][(kq*4 + r)*72 + u] = f2bfu(h_);
    }
    __builtin_amdgcn_sched_barrier(0);
    __builtin_amdgcn_s_waitcnt(WAIT_LGKM0);   // own ds_writes (incl. boundary writeG)
    __builtin_amdgcn_sched_barrier(0);
    __builtin_amdgcn_s_barrier();             // raw barrier: no vmcnt drain
  };

  auto sth = [&](int t, uint2 hv) __attribute__((always_inline)) {
    *reinterpret_cast<uint2*>(&hout[((size_t)t*512 + base + wm)*64 + wu]) = hv;
  };

  // -------- prologue: stage chunks 0,1 synchronously; chunk 2 in flight ----
  wait_for(j + 11*RATE);
  loadG(0); __builtin_amdgcn_s_waitcnt(WAIT_VM0); writeG(0);
  loadG(1); __builtin_amdgcn_s_waitcnt(WAIT_VM0); writeG(1);
  loadG(2);                                   // stays pending (counted)
  __builtin_amdgcn_s_waitcnt(WAIT_LGKM0);
  __builtin_amdgcn_s_barrier();

  uint2 hh0, hh1, hh2, hh3;
  stepc(0, &hh0);
  stepc(1, &hh1);
  stepc(2, &hh2);
  stepc(3, &hh3);
  sth(j,          hh1);
  sth(j +   RATE, hh2);
  sth(j + 2*RATE, hh3);

  int B = 4;
  for (; B + 4 <= nsteps; B += 4) {
    const int c = B >> 2;
    wait_for(j + (B + 11)*RATE);
    writeG((c + 1) & 1);     // chunk c+1 (G loaded at previous boundary)
    loadG(c + 2);            // next staging, consumed by writeG next boundary
    stepc(B+0, &hh0);
    stepc(B+1, &hh1);
    stepc(B+2, &hh2);
    stepc(B+3, &hh3);
    sth(j + (B-1)*RATE, hh0);
    sth(j + (B  )*RATE, hh1);
    sth(j + (B+1)*RATE, hh2);
    sth(j + (B+2)*RATE, hh3);
    if constexpr (LAYER < 3) {   // branchless every-chunk publish
      __builtin_amdgcn_s_waitcnt(WAIT_VM0);   // drain h-stores (loads ~4 steps old: done)
      __builtin_amdgcn_s_barrier();
      if (i == 0)
        __hip_atomic_store(myflag, B+3, __ATOMIC_RELEASE, __HIP_MEMORY_SCOPE_AGENT);
    }
  }
  for (; B < nsteps; ++B) {    // tail (<4 steps): x already staged; no new loads
    uint2 hvT;
    stepc(B, &hvT);
    sth(j + (B-1)*RATE, hvT);
  }

  // final h writeback + terminal publish
  {
    const int pF = nsteps & 1;
    const int tF = j + (nsteps - 1)*RATE;
    uint2 hv = *reinterpret_cast<const uint2*>(&hbuf[pF][wm*72 + wu]);
    sth(tF, hv);
  }
  if constexpr (LAYER < 3) {
    __builtin_amdgcn_s_waitcnt(WAIT_VM0);
    __builtin_amdgcn_s_barrier();
    if (i == 0)
      __hip_atomic_store(myflag, nsteps, __ATOMIC_RELEASE, __HIP_MEMORY_SCOPE_AGENT);
  }
}

__global__ __launch_bounds__(256, 2)
void lstm_fused(const ushort* __restrict__ xhat,
                ushort* __restrict__ h1, ushort* __restrict__ h2, ushort* __restrict__ h4,
                const float* __restrict__ Wih0, const float* __restrict__ Wih_rest,
                const float* __restrict__ Whh_all,
                const float* __restrict__ bih_all, const float* __restrict__ bhh_all,
                int* __restrict__ flags)
{
  const int bid = blockIdx.x;
  ushort* h3 = h1;   // alias safe: h1[t]'s only reader (L2) consumes it before
                     // h2[t] is published, which gates L3's write.
  if (bid < 32) {
    lstm_scan<1,0>(xhat, h1, Wih0, Whh_all, bih_all, bhh_all,
                   0, bid, flags);
  } else if (bid < 96) {
    lstm_scan<2,1>(h1, h2, Wih_rest, Whh_all + 256*64, bih_all + 256, bhh_all + 256,
                   (bid-32) >> 5, (bid-32) & 31, flags);
  } else if (bid < 224) {
    lstm_scan<2,2>(h2, h3, Wih_rest + 256*64, Whh_all + 2*256*64, bih_all + 2*256, bhh_all + 2*256,
                   (bid-96) >> 5, (bid-96) & 31, flags);
  } else {
    lstm_scan<2,3>(h3, h4, Wih_rest + 2*256*64, Whh_all + 3*256*64, bih_all + 3*256, bhh_all + 3*256,
                   (bid-224) >> 5, (bid-224) & 31, flags);
  }
}

// ---------------- adapter: out1 = (h4+h2) @ adW.T + adb ----------------
__global__ __launch_bounds__(256) void adapter_kernel(const ushort* __restrict__ h4, const ushort* __restrict__ h2,
      const float* __restrict__ adW, const float* __restrict__ adb, float* __restrict__ out) {
  __shared__ __align__(16) float xrow[64*64];
  const int i = threadIdx.x;
  const int total = T_WIN*512;
  const int base = blockIdx.x * 64;
  for (int e = i; e < 64*64; e += 256) {
    int r = e >> 6;
    size_t gi = (size_t)(base + r)*64 + (e & 63);
    float v = 0.f;
    if (base + r < total) {
      __hip_bfloat16 a = *reinterpret_cast<const __hip_bfloat16*>(h4 + gi);
      __hip_bfloat16 b = *reinterpret_cast<const __hip_bfloat16*>(h2 + gi);
      v = __bfloat162float(a) + __bfloat162float(b);
    }
    xrow[e] = v;
  }
  const int o  = i & 31;
  const int rg = i >> 5;
  float w[64]; float bo = 0.f;
  if (o < 28) {
    #pragma unroll
    for (int uu=0;uu<64;++uu) w[uu] = adW[o*64+uu];
    bo = adb[o];
  }
  __syncthreads();
  if (o < 28) {
    #pragma unroll
    for (int rr=0; rr<8; ++rr) {
      int r = rg*8 + rr;
      if (base + r >= total) break;
      const float4* xp = (const float4*)(&xrow[r*64]);
      float a0 = bo, a1 = 0.f, a2 = 0.f, a3 = 0.f;
      #pragma unroll
      for (int q=0;q<16;++q) {
        float4 xv = xp[q];
        a0 += w[4*q+0]*xv.x; a1 += w[4*q+1]*xv.y;
        a2 += w[4*q+2]*xv.z; a3 += w[4*q+3]*xv.w;
      }
      out[(size_t)(base+r)*28 + o] = (a0+a1)+(a2+a3);
    }
  }
}

extern "C" void kernel_launch(void* const* d_in, const int* in_sizes, int n_in,
                              void* d_out, int out_size, void* d_ws, size_t ws_size,
                              hipStream_t stream) {
  const float* y         = (const float*)d_in[0];
  const int*   idxs      = (const int*)d_in[1];
  const float* noise     = (const float*)d_in[2];
  const float* lev_sms   = (const float*)d_in[3];
  const float* seas_sms  = (const float*)d_in[4];
  const float* init_seas = (const float*)d_in[5];
  const float* Wih0      = (const float*)d_in[6];
  const float* Wih_rest  = (const float*)d_in[7];
  const float* Whh_all   = (const float*)d_in[8];
  const float* bih_all   = (const float*)d_in[9];
  const float* bhh_all   = (const float*)d_in[10];
  const float* adW       = (const float*)d_in[11];
  const float* adb       = (const float*)d_in[12];

  const size_t NWIN28 = (size_t)T_WIN*512*28;
  const size_t NWIN64 = (size_t)T_WIN*512*64;
  float* out_wy   = (float*)d_out;
  float* out_yhat = out_wy + NWIN28;
  float* out_lev  = out_yhat + NWIN28;

  int*   flags = (int*)d_ws;                       // 4 KiB reserved
  float* seas  = (float*)((char*)d_ws + 4096);
  float* lnorm = seas  + (size_t)NSER*NTIME;
  float* llev  = lnorm + (size_t)NSER*NTIME;
  ushort* xhat = (ushort*)(llev + (size_t)NSER*NTIME);
  ushort* h1   = (ushort*)((char*)xhat + NWIN28*2);
  ushort* h2   = (ushort*)((char*)h1 + NWIN64*2);
  ushort* h4   = (ushort*)((char*)h2 + NWIN64*2);

  size_t need = 4096 + (size_t)3*NSER*NTIME*4 + NWIN28*2 + 3*NWIN64*2;
  if (ws_size < need) {
    fprintf(stderr, "kernel_launch: ws_size %zu < needed %zu\n", ws_size, need);
    return;
  }

  hipMemsetAsync(flags, 0, FLAGS_INTS*sizeof(int), stream);
  es_kernel<<<2,256,0,stream>>>(y, idxs, lev_sms, seas_sms, init_seas, out_lev, seas);
  lnorm_kernel<<<(NSER*NTIME)/256,256,0,stream>>>(y, seas, out_lev, lnorm, llev);
  window_kernel<<<NWIN28/256,256,0,stream>>>(lnorm, llev, noise, out_wy, xhat);

  lstm_fused<<<480,256,0,stream>>>(xhat, h1, h2, h4, Wih0, Wih_rest, Whh_all,
                                   bih_all, bhh_all, flags);

  adapter_kernel<<<(T_WIN*512)/64,256,0,stream>>>(h4, h2, adW, adb, out_yhat);
}